// Round 11
// baseline (1022.342 us; speedup 1.0000x reference)
//
#include <hip/hip_runtime.h>

#define BB 64
#define SS 512
#define DD 768
#define D4 192   // DD/4

typedef float v4f __attribute__((ext_vector_type(4)));

// Kernel A: tW[b][d] = sum_k topic[b][k] * W[k][d]   (R4-proven shape)
// grid (64, 12), block 256. One b, 64 d's (16 float4), 16-way k-split,
// unroll-8 float4 W loads, LDS reduce. Also zeroes the per-b tail counters.
__global__ void tw_kernel(const float* __restrict__ topic,
                          const float* __restrict__ W,
                          float* __restrict__ tW,
                          int* __restrict__ cnt) {
    __shared__ float t_s[DD];
    __shared__ float4 red[16][16];
    const int b  = blockIdx.x;
    const int t  = threadIdx.x;
    const int dl = t & 15;            // float4 slot within the 64-d tile
    const int kg = t >> 4;            // 0..15
    const int d4 = blockIdx.y * 16;   // tile start in float4 units

    if (blockIdx.x == 0 && blockIdx.y == 0 && t < BB) cnt[t] = 0;

    for (int k = t; k < DD; k += 256) t_s[k] = topic[b * DD + k];
    __syncthreads();

    const float4* __restrict__ W4 = (const float4*)W;  // [DD][D4]
    const int k0 = kg * 48;
    float4 acc = make_float4(0.f, 0.f, 0.f, 0.f);
#pragma unroll 8
    for (int k = 0; k < 48; ++k) {
        const float ts = t_s[k0 + k];
        const float4 w = W4[(size_t)(k0 + k) * D4 + d4 + dl];
        acc.x = fmaf(ts, w.x, acc.x);
        acc.y = fmaf(ts, w.y, acc.y);
        acc.z = fmaf(ts, w.z, acc.z);
        acc.w = fmaf(ts, w.w, acc.w);
    }
    red[kg][dl] = acc;
    __syncthreads();

    if (t < 16) {
        float4 s = red[0][t];
#pragma unroll
        for (int j = 1; j < 16; ++j) {
            const float4 r = red[j][t];
            s.x += r.x; s.y += r.y; s.z += r.z; s.w += r.w;
        }
        ((float4*)tW)[(size_t)b * D4 + d4 + t] = s;
    }
}

// Kernel B: scores + fused softmax tail.
// One wave per (b,s), 4 waves/block (one block never straddles b: 4 | 512).
// After writing its 4 scores, each block bumps cnt[b]; the 128th block for b
// acquires and runs the 512-wide softmax for that b (split-K tail pattern).
__global__ void score_kernel(const float* __restrict__ tW,
                             const float* __restrict__ seq,
                             const float* __restrict__ bias,
                             float* __restrict__ scores,
                             int* __restrict__ cnt,
                             float* __restrict__ out) {
    __shared__ int amLast;
    __shared__ float sred[4];
    __shared__ float s_m, s_sum;

    const int tid  = threadIdx.x;
    const int wv   = tid >> 6;
    const int lane = tid & 63;
    const int b    = blockIdx.x >> 7;            // 128 blocks per b
    const int gwid = (int)blockIdx.x * 4 + wv;
    const int s    = gwid & (SS - 1);

    const v4f* sp = (const v4f*)(seq + ((size_t)b * SS + s) * DD);
    const float4* tp = (const float4*)(tW + (size_t)b * DD);

    float acc = 0.f;
#pragma unroll
    for (int k = 0; k < 3; ++k) {
        const v4f x = __builtin_nontemporal_load(sp + lane + k * 64);
        const float4 t = tp[lane + k * 64];
        acc = fmaf(x.x, t.x, acc);
        acc = fmaf(x.y, t.y, acc);
        acc = fmaf(x.z, t.z, acc);
        acc = fmaf(x.w, t.w, acc);
    }
#pragma unroll
    for (int off = 32; off >= 1; off >>= 1) acc += __shfl_xor(acc, off);

    if (lane == 0) scores[(size_t)b * SS + s] = acc + bias[0];

    // ---- completion count (release) ----
    __threadfence();
    if (tid == 0) {
        const int old = atomicAdd(&cnt[b], 1);
        amLast = (old == 127);
    }
    __syncthreads();
    if (!amLast) return;

    // ---- softmax tail for this b (acquire) ----
    __threadfence();
    const float v0 = scores[(size_t)b * SS + tid];
    const float v1 = scores[(size_t)b * SS + tid + 256];

    float m = fmaxf(v0, v1);
#pragma unroll
    for (int off = 32; off >= 1; off >>= 1) m = fmaxf(m, __shfl_xor(m, off));
    if (lane == 0) sred[wv] = m;
    __syncthreads();
    if (tid == 0) s_m = fmaxf(fmaxf(sred[0], sred[1]), fmaxf(sred[2], sred[3]));
    __syncthreads();

    const float e0 = __expf(v0 - s_m);
    const float e1 = __expf(v1 - s_m);
    float sum = e0 + e1;
#pragma unroll
    for (int off = 32; off >= 1; off >>= 1) sum += __shfl_xor(sum, off);
    if (lane == 0) sred[wv] = sum;
    __syncthreads();
    if (tid == 0) s_sum = (sred[0] + sred[1]) + (sred[2] + sred[3]);
    __syncthreads();

    const float inv = 1.f / s_sum;
    out[(size_t)b * SS + tid]       = e0 * inv;
    out[(size_t)b * SS + tid + 256] = e1 * inv;
}

extern "C" void kernel_launch(void* const* d_in, const int* in_sizes, int n_in,
                              void* d_out, int out_size, void* d_ws, size_t ws_size,
                              hipStream_t stream) {
    const float* topic = (const float*)d_in[0];
    const float* seq   = (const float*)d_in[1];
    const float* W     = (const float*)d_in[2];
    const float* bias  = (const float*)d_in[3];
    float* out = (float*)d_out;

    float* tW     = (float*)d_ws;                 // BB*DD floats
    float* scores = tW + (size_t)BB * DD;         // BB*SS floats
    int*   cnt    = (int*)(scores + (size_t)BB * SS);  // BB ints

    tw_kernel<<<dim3(BB, 12), 256, 0, stream>>>(topic, W, tW, cnt);

    const int blocks = (BB * SS) / 4;             // 4 waves (scores) per block
    score_kernel<<<blocks, 256, 0, stream>>>(tW, seq, bias, scores, cnt, out);
}

// Round 12
// 28.228 us; speedup vs baseline: 36.2174x; 36.2174x over previous
//
#include <hip/hip_runtime.h>

#define BB 64
#define SS 512
#define DD 768
#define D4 192   // DD/4

typedef float v4f __attribute__((ext_vector_type(4)));

// Kernel A (BG=2, line-exact): tW[b][d] = sum_k topic[b][k] * W[k][d]
// grid (32, 24), block 256. Each block: 2 b's, 32 d's (8 float4), full K=768.
// dl=t&7 -> 8 lanes x 16B = one full 128B line per row-segment (128B-aligned).
// kg=t>>3 -> 32 k-chains of 24, fully unrolled (24 loads in flight).
// 768 blocks (even 3/CU) AND 2x W-reuse (75.5 MB L2 traffic).
__global__ void tw_kernel(const float* __restrict__ topic,
                          const float* __restrict__ W,
                          float* __restrict__ tW) {
    __shared__ float  t_s[2][DD];          // 6 KB
    __shared__ float4 red[4][2][8];        // 1 KB
    const int t    = threadIdx.x;
    const int b0   = blockIdx.x * 2;
    const int d4   = blockIdx.y * 8;       // tile start in float4 units
    const int dl   = t & 7;
    const int kg   = t >> 3;               // 0..31
    const int wv   = t >> 6;               // 0..3
    const int lane = t & 63;

    // stage 2 contiguous topic rows (384 float4s)
    {
        const float4* tp  = (const float4*)topic + (size_t)b0 * D4;
        float4*       ts4 = (float4*)t_s;
        ts4[t] = tp[t];
        if (t < 128) ts4[t + 256] = tp[t + 256];
    }
    __syncthreads();

    const float4* __restrict__ W4 = (const float4*)W;  // [DD][D4]
    const int k0 = kg * 24;
    float4 a0 = make_float4(0.f, 0.f, 0.f, 0.f);
    float4 a1 = make_float4(0.f, 0.f, 0.f, 0.f);

#pragma unroll
    for (int k = 0; k < 24; ++k) {
        const float4 w  = W4[(size_t)(k0 + k) * D4 + d4 + dl];
        const float  s0 = t_s[0][k0 + k];
        const float  s1 = t_s[1][k0 + k];
        a0.x = fmaf(s0, w.x, a0.x); a0.y = fmaf(s0, w.y, a0.y);
        a0.z = fmaf(s0, w.z, a0.z); a0.w = fmaf(s0, w.w, a0.w);
        a1.x = fmaf(s1, w.x, a1.x); a1.y = fmaf(s1, w.y, a1.y);
        a1.z = fmaf(s1, w.z, a1.z); a1.w = fmaf(s1, w.w, a1.w);
    }

    // in-wave reduce across the 8 kg's resident in this wave (lane bits 3..5)
#pragma unroll
    for (int off = 8; off <= 32; off <<= 1) {
        a0.x += __shfl_xor(a0.x, off); a0.y += __shfl_xor(a0.y, off);
        a0.z += __shfl_xor(a0.z, off); a0.w += __shfl_xor(a0.w, off);
        a1.x += __shfl_xor(a1.x, off); a1.y += __shfl_xor(a1.y, off);
        a1.z += __shfl_xor(a1.z, off); a1.w += __shfl_xor(a1.w, off);
    }
    if (lane < 8) {                        // lane == dl here
        red[wv][0][lane] = a0;
        red[wv][1][lane] = a1;
    }
    __syncthreads();

    if (t < 16) {
        const int bi = t >> 3, d = t & 7;
        const float4 s0 = red[0][bi][d], s1 = red[1][bi][d];
        const float4 s2 = red[2][bi][d], s3 = red[3][bi][d];
        float4 s;
        s.x = (s0.x + s1.x) + (s2.x + s3.x);
        s.y = (s0.y + s1.y) + (s2.y + s3.y);
        s.z = (s0.z + s1.z) + (s2.z + s3.z);
        s.w = (s0.w + s1.w) + (s2.w + s3.w);
        ((float4*)tW)[(size_t)(b0 + bi) * D4 + d4 + d] = s;
    }
}

// Kernel B: scores[b][s] = dot(tW[b], seq[b][s]) + bias   (R4-proven, byte-identical)
__global__ void score_kernel(const float* __restrict__ tW,
                             const float* __restrict__ seq,
                             const float* __restrict__ bias,
                             float* __restrict__ scores) {
    const int gwid = (int)((blockIdx.x * blockDim.x + threadIdx.x) >> 6);
    const int lane = threadIdx.x & 63;
    const int b = gwid >> 9;      // / SS
    const int s = gwid & (SS - 1);

    const v4f* sp = (const v4f*)(seq + ((size_t)b * SS + s) * DD);
    const float4* tp = (const float4*)(tW + (size_t)b * DD);

    float acc = 0.f;
#pragma unroll
    for (int k = 0; k < 3; ++k) {
        const v4f x = __builtin_nontemporal_load(sp + lane + k * 64);
        const float4 t = tp[lane + k * 64];
        acc = fmaf(x.x, t.x, acc);
        acc = fmaf(x.y, t.y, acc);
        acc = fmaf(x.z, t.z, acc);
        acc = fmaf(x.w, t.w, acc);
    }
#pragma unroll
    for (int off = 32; off >= 1; off >>= 1) acc += __shfl_xor(acc, off);

    if (lane == 0) scores[gwid] = acc + bias[0];
}

// Kernel C: beta[b] = softmax(scores[b]) over S. One block of 512 per b.
__global__ void softmax_kernel(const float* __restrict__ scores,
                               float* __restrict__ beta) {
    __shared__ float red[8];
    __shared__ float s_m, s_sum;
    const int b   = blockIdx.x;
    const int tid = threadIdx.x;          // 0..511
    const int wid = tid >> 6, lane = tid & 63;

    const float v = scores[b * SS + tid];

    float m = v;
#pragma unroll
    for (int off = 32; off >= 1; off >>= 1) m = fmaxf(m, __shfl_xor(m, off));
    if (lane == 0) red[wid] = m;
    __syncthreads();
    if (tid == 0) {
        float mm = red[0];
#pragma unroll
        for (int i = 1; i < 8; ++i) mm = fmaxf(mm, red[i]);
        s_m = mm;
    }
    __syncthreads();

    const float e = __expf(v - s_m);
    float sum = e;
#pragma unroll
    for (int off = 32; off >= 1; off >>= 1) sum += __shfl_xor(sum, off);
    if (lane == 0) red[wid] = sum;
    __syncthreads();
    if (tid == 0) {
        float ss = 0.f;
#pragma unroll
        for (int i = 0; i < 8; ++i) ss += red[i];
        s_sum = ss;
    }
    __syncthreads();

    beta[b * SS + tid] = e / s_sum;
}

extern "C" void kernel_launch(void* const* d_in, const int* in_sizes, int n_in,
                              void* d_out, int out_size, void* d_ws, size_t ws_size,
                              hipStream_t stream) {
    const float* topic = (const float*)d_in[0];
    const float* seq   = (const float*)d_in[1];
    const float* W     = (const float*)d_in[2];
    const float* bias  = (const float*)d_in[3];
    float* out = (float*)d_out;

    float* tW     = (float*)d_ws;                 // BB*DD floats
    float* scores = tW + (size_t)BB * DD;         // BB*SS floats

    tw_kernel<<<dim3(BB / 2, 24), 256, 0, stream>>>(topic, W, tW);

    const int total_waves = BB * SS;              // one wave per score
    const int blocks = (total_waves * 64) / 256;  // 4 waves per block
    score_kernel<<<blocks, 256, 0, stream>>>(tW, seq, bias, scores);

    softmax_kernel<<<BB, 512, 0, stream>>>(scores, out);
}